// Round 1
// baseline (592.011 us; speedup 1.0000x reference)
//
#include <hip/hip_runtime.h>

#define B_  4
#define S_  2048
#define D_  1024
#define H_  16
#define HD_ 64
#define BS_ (B_*S_)   // 8192

typedef __bf16 bf16_8 __attribute__((ext_vector_type(8)));
typedef float  f32_4  __attribute__((ext_vector_type(4)));

__device__ inline unsigned short f2bf(float f) {
    unsigned u = __float_as_uint(f);
    u += 0x7FFF + ((u >> 16) & 1);          // RNE
    return (unsigned short)(u >> 16);
}

__device__ inline uint4 pack8(const float f[8]) {
    uint4 r;
    r.x = (unsigned)f2bf(f[0]) | ((unsigned)f2bf(f[1]) << 16);
    r.y = (unsigned)f2bf(f[2]) | ((unsigned)f2bf(f[3]) << 16);
    r.z = (unsigned)f2bf(f[4]) | ((unsigned)f2bf(f[5]) << 16);
    r.w = (unsigned)f2bf(f[6]) | ((unsigned)f2bf(f[7]) << 16);
    return r;
}

// ---------------------------------------------------------------------------
// GEMM1: qkv = x @ W_attn + b_attn ; scatter to Q/K/V [B,H,S,HD] bf16
// ---------------------------------------------------------------------------
__global__ __launch_bounds__(256) void qkv_gemm(
    const float* __restrict__ X,      // [8192,1024]
    const float* __restrict__ W,      // [1024,3072]
    const float* __restrict__ bias,   // [3072]
    unsigned short* __restrict__ Qb,
    unsigned short* __restrict__ Kb,
    unsigned short* __restrict__ Vb)
{
    __shared__ unsigned short As[64*40];   // [m][k], stride 40 (pad: 20 words)
    __shared__ unsigned short Bs[64*40];   // B^T: [n][k]
    const int t    = threadIdx.x;
    const int lane = t & 63;
    const int w    = t >> 6;
    const int quad = lane >> 4;
    const int l15  = lane & 15;
    const int n0   = blockIdx.x * 64;
    const int m0   = blockIdx.y * 64;

    f32_4 c[2][2] = {};

    const int am = t >> 2;           // 0..63
    const int ak = (t & 3) * 8;      // 0,8,16,24
    const int bn = t & 63;           // 0..63
    const int bk = (t >> 6) * 8;     // 0,8,16,24
    const int mb = (w >> 1) * 32;
    const int nb = (w & 1) * 32;

    for (int k0 = 0; k0 < 1024; k0 += 32) {
        {   // stage A (fp32 -> bf16), coalesced 32B/thread
            const float* src = X + (size_t)(m0 + am) * 1024 + k0 + ak;
            float4 a0 = *(const float4*)src;
            float4 a1 = *(const float4*)(src + 4);
            float f[8] = {a0.x,a0.y,a0.z,a0.w,a1.x,a1.y,a1.z,a1.w};
            *(uint4*)&As[am*40 + ak] = pack8(f);
        }
        {   // stage B transposed: coalesced global (lanes span n), 16B LDS store
            float f[8];
            #pragma unroll
            for (int i = 0; i < 8; i++)
                f[i] = W[(size_t)(k0 + bk + i) * 3072 + n0 + bn];
            *(uint4*)&Bs[bn*40 + bk] = pack8(f);
        }
        __syncthreads();
        bf16_8 a0 = *(const bf16_8*)&As[(mb      + l15)*40 + quad*8];
        bf16_8 a1 = *(const bf16_8*)&As[(mb + 16 + l15)*40 + quad*8];
        bf16_8 b0 = *(const bf16_8*)&Bs[(nb      + l15)*40 + quad*8];
        bf16_8 b1 = *(const bf16_8*)&Bs[(nb + 16 + l15)*40 + quad*8];
        c[0][0] = __builtin_amdgcn_mfma_f32_16x16x32_bf16(a0, b0, c[0][0], 0,0,0);
        c[0][1] = __builtin_amdgcn_mfma_f32_16x16x32_bf16(a0, b1, c[0][1], 0,0,0);
        c[1][0] = __builtin_amdgcn_mfma_f32_16x16x32_bf16(a1, b0, c[1][0], 0,0,0);
        c[1][1] = __builtin_amdgcn_mfma_f32_16x16x32_bf16(a1, b1, c[1][1], 0,0,0);
        __syncthreads();
    }
    // epilogue: bias + scatter into [B,H,S,HD]
    #pragma unroll
    for (int mi = 0; mi < 2; mi++)
    #pragma unroll
    for (int ni = 0; ni < 2; ni++)
    #pragma unroll
    for (int r = 0; r < 4; r++) {
        int m = m0 + mb + mi*16 + quad*4 + r;        // row in [0,8192)
        int n = n0 + nb + ni*16 + l15;               // col in [0,3072)
        float v = c[mi][ni][r] + bias[n];
        int which = n >> 10;
        int dcol  = n & 1023;
        int h  = dcol >> 6, hd = dcol & 63;
        int b  = m >> 11,  s  = m & 2047;
        int idx = ((b*16 + h)*2048 + s)*64 + hd;
        unsigned short bv = f2bf(v);
        if      (which == 0) Qb[idx] = bv;
        else if (which == 1) Kb[idx] = bv;
        else                 Vb[idx] = bv;
    }
}

// ---------------------------------------------------------------------------
// Flash causal attention: one block = (b,h, 64 query rows), 4 waves x 16 rows
// ---------------------------------------------------------------------------
__global__ __launch_bounds__(256) void attn(
    const unsigned short* __restrict__ Qb,
    const unsigned short* __restrict__ Kb,
    const unsigned short* __restrict__ Vb,
    unsigned short* __restrict__ Y)    // [8192,1024] bf16, col = h*64+hd
{
    __shared__ unsigned short Ks[32*72];     // [key][hd]  stride 72 (36 words)
    __shared__ unsigned short Vt[64*40];     // V^T [hd][key] stride 40
    __shared__ unsigned short Pl[4][16*40];  // per-wave P round-trip

    const int t    = threadIdx.x;
    const int w    = t >> 6;
    const int lane = t & 63;
    const int quad = lane >> 4, l15 = lane & 15;
    const int bh = blockIdx.y;               // b*16+h
    const int b  = bh >> 4, h = bh & 15;
    const int qw = blockIdx.x * 64 + w * 16; // this wave's first q row

    const unsigned short* qh = Qb + (size_t)bh * S_ * 64;
    const unsigned short* kh = Kb + (size_t)bh * S_ * 64;
    const unsigned short* vh = Vb + (size_t)bh * S_ * 64;

    bf16_8 qa0 = *(const bf16_8*)&qh[(qw + l15)*64 +      quad*8];
    bf16_8 qa1 = *(const bf16_8*)&qh[(qw + l15)*64 + 32 + quad*8];

    f32_4 o[4] = {};
    float m_r[4], l_r[4];
    #pragma unroll
    for (int r = 0; r < 4; r++) { m_r[r] = -__builtin_inff(); l_r[r] = 0.f; }

    const int ntiles = 2*blockIdx.x + 2;
    const int sk  = t >> 3;          // key   0..31
    const int sh  = (t & 7) * 8;     // hd    0..56
    const int vhd = t & 63;          // hd    0..63
    const int vk  = (t >> 6) * 8;    // key   0,8,16,24

    for (int kt = 0; kt < ntiles; kt++) {
        const int kbase = kt * 32;
        // stage K tile [key][hd] (16B copies, coalesced)
        *(uint4*)&Ks[sk*72 + sh] = *(const uint4*)&kh[(kbase + sk)*64 + sh];
        // stage V^T [hd][key]: coalesced global reads, 16B LDS store
        {
            unsigned short tmp[8];
            #pragma unroll
            for (int i = 0; i < 8; i++)
                tmp[i] = vh[(kbase + vk + i)*64 + vhd];
            *(uint4*)&Vt[vhd*40 + vk] = *(uint4*)tmp;
        }
        __syncthreads();

        // S = Q K^T  (two 16-key subtiles, K-dim=64 in two MFMA chunks)
        f32_4 s[2];
        #pragma unroll
        for (int sub = 0; sub < 2; sub++) {
            bf16_8 kb0 = *(const bf16_8*)&Ks[(sub*16 + l15)*72 +      quad*8];
            bf16_8 kb1 = *(const bf16_8*)&Ks[(sub*16 + l15)*72 + 32 + quad*8];
            f32_4 acc = {};
            acc = __builtin_amdgcn_mfma_f32_16x16x32_bf16(qa0, kb0, acc, 0,0,0);
            acc = __builtin_amdgcn_mfma_f32_16x16x32_bf16(qa1, kb1, acc, 0,0,0);
            s[sub] = acc;
        }

        // online softmax (rows: quad*4+r, cols: l15 within 16-lane group)
        float p0v[4], p1v[4], alpha[4];
        #pragma unroll
        for (int r = 0; r < 4; r++) {
            int row = qw + quad*4 + r;
            float v0 = (kbase      + l15 <= row) ? s[0][r]*0.125f : -__builtin_inff();
            float v1 = (kbase + 16 + l15 <= row) ? s[1][r]*0.125f : -__builtin_inff();
            float mx = fmaxf(v0, v1);
            #pragma unroll
            for (int off = 1; off < 16; off <<= 1)
                mx = fmaxf(mx, __shfl_xor(mx, off, 64));
            float nm = fmaxf(m_r[r], mx);
            float p0 = __expf(v0 - nm);
            float p1 = __expf(v1 - nm);
            float sm = p0 + p1;
            #pragma unroll
            for (int off = 1; off < 16; off <<= 1)
                sm += __shfl_xor(sm, off, 64);
            alpha[r] = __expf(m_r[r] - nm);
            m_r[r] = nm;
            l_r[r] = l_r[r]*alpha[r] + sm;
            p0v[r] = p0; p1v[r] = p1;
        }
        #pragma unroll
        for (int tt = 0; tt < 4; tt++)
            #pragma unroll
            for (int r = 0; r < 4; r++)
                o[tt][r] *= alpha[r];

        // P: C-layout -> LDS -> A-layout (per-wave region, wave-local sync)
        #pragma unroll
        for (int r = 0; r < 4; r++) {
            Pl[w][(quad*4+r)*40 +      l15] = f2bf(p0v[r]);
            Pl[w][(quad*4+r)*40 + 16 + l15] = f2bf(p1v[r]);
        }
        asm volatile("s_waitcnt lgkmcnt(0)" ::: "memory");
        bf16_8 pa = *(const bf16_8*)&Pl[w][l15*40 + quad*8];

        // O += P V
        #pragma unroll
        for (int tt = 0; tt < 4; tt++) {
            bf16_8 vb = *(const bf16_8*)&Vt[(tt*16 + l15)*40 + quad*8];
            o[tt] = __builtin_amdgcn_mfma_f32_16x16x32_bf16(pa, vb, o[tt], 0,0,0);
        }
        __syncthreads();
    }

    // epilogue: divide by l, write y [b*S+s][h*64+hd] bf16
    #pragma unroll
    for (int tt = 0; tt < 4; tt++)
        #pragma unroll
        for (int r = 0; r < 4; r++) {
            int srow = qw + quad*4 + r;
            int col  = h*64 + tt*16 + l15;
            float v = o[tt][r] / l_r[r];
            Y[(size_t)(b*S_ + srow)*1024 + col] = f2bf(v);
        }
}

// ---------------------------------------------------------------------------
// GEMM2: out = y @ W_proj + b_proj  (A bf16 from ws, B fp32, C fp32)
// ---------------------------------------------------------------------------
__global__ __launch_bounds__(256) void proj_gemm(
    const unsigned short* __restrict__ Yb,  // [8192,1024] bf16
    const float* __restrict__ W,            // [1024,1024]
    const float* __restrict__ bias,         // [1024]
    float* __restrict__ Out)                // [8192,1024]
{
    __shared__ unsigned short As[64*40];
    __shared__ unsigned short Bs[64*40];
    const int t    = threadIdx.x;
    const int lane = t & 63;
    const int w    = t >> 6;
    const int quad = lane >> 4;
    const int l15  = lane & 15;
    const int n0   = blockIdx.x * 64;
    const int m0   = blockIdx.y * 64;

    f32_4 c[2][2] = {};
    const int am = t >> 2;
    const int ak = (t & 3) * 8;
    const int bn = t & 63;
    const int bk = (t >> 6) * 8;
    const int mb = (w >> 1) * 32;
    const int nb = (w & 1) * 32;

    for (int k0 = 0; k0 < 1024; k0 += 32) {
        *(uint4*)&As[am*40 + ak] =
            *(const uint4*)&Yb[(size_t)(m0 + am)*1024 + k0 + ak];
        {
            float f[8];
            #pragma unroll
            for (int i = 0; i < 8; i++)
                f[i] = W[(size_t)(k0 + bk + i)*1024 + n0 + bn];
            *(uint4*)&Bs[bn*40 + bk] = pack8(f);
        }
        __syncthreads();
        bf16_8 a0 = *(const bf16_8*)&As[(mb      + l15)*40 + quad*8];
        bf16_8 a1 = *(const bf16_8*)&As[(mb + 16 + l15)*40 + quad*8];
        bf16_8 b0 = *(const bf16_8*)&Bs[(nb      + l15)*40 + quad*8];
        bf16_8 b1 = *(const bf16_8*)&Bs[(nb + 16 + l15)*40 + quad*8];
        c[0][0] = __builtin_amdgcn_mfma_f32_16x16x32_bf16(a0, b0, c[0][0], 0,0,0);
        c[0][1] = __builtin_amdgcn_mfma_f32_16x16x32_bf16(a0, b1, c[0][1], 0,0,0);
        c[1][0] = __builtin_amdgcn_mfma_f32_16x16x32_bf16(a1, b0, c[1][0], 0,0,0);
        c[1][1] = __builtin_amdgcn_mfma_f32_16x16x32_bf16(a1, b1, c[1][1], 0,0,0);
        __syncthreads();
    }
    #pragma unroll
    for (int mi = 0; mi < 2; mi++)
    #pragma unroll
    for (int ni = 0; ni < 2; ni++)
    #pragma unroll
    for (int r = 0; r < 4; r++) {
        int m = m0 + mb + mi*16 + quad*4 + r;
        int n = n0 + nb + ni*16 + l15;
        Out[(size_t)m*1024 + n] = c[mi][ni][r] + bias[n];
    }
}

// ---------------------------------------------------------------------------
extern "C" void kernel_launch(void* const* d_in, const int* in_sizes, int n_in,
                              void* d_out, int out_size, void* d_ws, size_t ws_size,
                              hipStream_t stream) {
    const float* x      = (const float*)d_in[0];
    const float* W_attn = (const float*)d_in[1];
    const float* b_attn = (const float*)d_in[2];
    const float* W_proj = (const float*)d_in[3];
    const float* b_proj = (const float*)d_in[4];
    float* out = (float*)d_out;

    const size_t per = (size_t)B_ * H_ * S_ * HD_;   // 8,388,608 elems
    unsigned short* Qb = (unsigned short*)d_ws;
    unsigned short* Kb = Qb + per;
    unsigned short* Vb = Kb + per;
    unsigned short* Yb = Vb + per;                    // total 64 MB

    qkv_gemm<<<dim3(3*D_/64, BS_/64), 256, 0, stream>>>(x, W_attn, b_attn, Qb, Kb, Vb);
    attn    <<<dim3(S_/64, B_*H_),    256, 0, stream>>>(Qb, Kb, Vb, Yb);
    proj_gemm<<<dim3(D_/64, BS_/64),  256, 0, stream>>>(Yb, W_proj, b_proj, out);
}

// Round 2
// 542.575 us; speedup vs baseline: 1.0911x; 1.0911x over previous
//
#include <hip/hip_runtime.h>

#define B_  4
#define S_  2048
#define D_  1024
#define H_  16
#define HD_ 64
#define BS_ (B_*S_)   // 8192

typedef _Float16 f16;
typedef _Float16 f16_8 __attribute__((ext_vector_type(8)));
typedef float    f32_4 __attribute__((ext_vector_type(4)));

#define MFMA16(a,b,c) __builtin_amdgcn_mfma_f32_16x16x32_f16(a, b, c, 0, 0, 0)
#define NEG_INF (-__builtin_inff())

// ---------------------------------------------------------------------------
// GEMM1: qkv = x @ W_attn + b_attn
//   Q -> [bh][s][hd] f16, pre-scaled by (1/sqrt(HD))*log2(e)  (exp2 units)
//   K -> [bh][s][hd] f16
//   V -> [bh][hd][s] f16  (pre-transposed for attention's B-operand)
// ---------------------------------------------------------------------------
__global__ __launch_bounds__(256) void qkv_gemm(
    const float* __restrict__ X,      // [8192,1024]
    const float* __restrict__ W,      // [1024,3072]
    const float* __restrict__ bias,   // [3072]
    f16* __restrict__ Qb, f16* __restrict__ Kb, f16* __restrict__ Vt)
{
    __shared__ f16 As[64*40];   // [m][k] stride 40 (80B = 16B-aligned rows)
    __shared__ f16 Bs[64*40];   // B^T [n][k]
    const int t    = threadIdx.x;
    const int lane = t & 63;
    const int w    = t >> 6;
    const int quad = lane >> 4, l15 = lane & 15;
    const int n0   = blockIdx.x * 64;
    const int m0   = blockIdx.y * 64;

    f32_4 c[2][2] = {};
    const int am = t >> 2, ak = (t & 3) * 8;
    const int bn = t & 63, bk = (t >> 6) * 8;
    const int mb = (w >> 1) * 32, nb = (w & 1) * 32;

    for (int k0 = 0; k0 < 1024; k0 += 32) {
        {   // stage A (fp32 -> f16), 32B/thread coalesced
            const float* src = X + (size_t)(m0 + am) * 1024 + k0 + ak;
            float4 a0 = *(const float4*)src;
            float4 a1 = *(const float4*)(src + 4);
            f16 h[8] = {(f16)a0.x,(f16)a0.y,(f16)a0.z,(f16)a0.w,
                        (f16)a1.x,(f16)a1.y,(f16)a1.z,(f16)a1.w};
            *(uint4*)&As[am*40 + ak] = *(const uint4*)h;
        }
        {   // stage B transposed (lanes span n: coalesced)
            f16 h[8];
            #pragma unroll
            for (int i = 0; i < 8; i++)
                h[i] = (f16)W[(size_t)(k0 + bk + i) * 3072 + n0 + bn];
            *(uint4*)&Bs[bn*40 + bk] = *(const uint4*)h;
        }
        __syncthreads();
        f16_8 a0 = *(const f16_8*)&As[(mb      + l15)*40 + quad*8];
        f16_8 a1 = *(const f16_8*)&As[(mb + 16 + l15)*40 + quad*8];
        f16_8 b0 = *(const f16_8*)&Bs[(nb      + l15)*40 + quad*8];
        f16_8 b1 = *(const f16_8*)&Bs[(nb + 16 + l15)*40 + quad*8];
        c[0][0] = MFMA16(a0, b0, c[0][0]);
        c[0][1] = MFMA16(a0, b1, c[0][1]);
        c[1][0] = MFMA16(a1, b0, c[1][0]);
        c[1][1] = MFMA16(a1, b1, c[1][1]);
        __syncthreads();
    }

    const float QSC = 0.125f * 1.44269504f;   // 1/sqrt(64) * log2(e)
    #pragma unroll
    for (int mi = 0; mi < 2; mi++)
    #pragma unroll
    for (int ni = 0; ni < 2; ni++)
    #pragma unroll
    for (int r = 0; r < 4; r++) {
        int m = m0 + mb + mi*16 + quad*4 + r;   // row in [0,8192)
        int n = n0 + nb + ni*16 + l15;          // col in [0,3072)
        float v = c[mi][ni][r] + bias[n];
        int which = n >> 10, dcol = n & 1023;
        int h = dcol >> 6, hd = dcol & 63;
        int b = m >> 11,  s  = m & 2047;
        size_t bh = (size_t)(b*16 + h);
        if      (which == 0) Qb[(bh*2048 + s)*64 + hd] = (f16)(v * QSC);
        else if (which == 1) Kb[(bh*2048 + s)*64 + hd] = (f16)v;
        else                 Vt[(bh*64 + hd)*2048 + s] = (f16)v;
    }
}

// ---------------------------------------------------------------------------
// Flash causal attention: block = (b,h, 128 q rows), 4 waves x 32 rows,
// 64-key tiles. Scores arrive in exp2 units (scale folded into Q).
// ---------------------------------------------------------------------------
__global__ __launch_bounds__(256) void attn(
    const f16* __restrict__ Qb,
    const f16* __restrict__ Kb,
    const f16* __restrict__ Vt,     // [bh][hd][s]
    f16* __restrict__ Y)            // [8192,1024], col = h*64+hd
{
    __shared__ f16 Ks[64*72];       // [key][hd]  stride 72 (144B, 16B-aligned)
    __shared__ f16 Vs[64*72];       // V^T [hd][key]
    __shared__ f16 Pl[4][32*72];    // per-wave P round-trip

    const int t    = threadIdx.x;
    const int w    = t >> 6;
    const int lane = t & 63;
    const int quad = lane >> 4, l15 = lane & 15;
    const int bh   = blockIdx.y;
    const int b    = bh >> 4, h = bh & 15;
    const int qb   = blockIdx.x;
    const int qw   = qb*128 + w*32;          // wave's first q row

    const f16* qh = Qb + (size_t)bh * S_ * 64;
    const f16* kh = Kb + (size_t)bh * S_ * 64;
    const f16* vt = Vt + (size_t)bh * 64 * S_;

    f16_8 qa[2][2];
    #pragma unroll
    for (int rt = 0; rt < 2; rt++)
        #pragma unroll
        for (int c = 0; c < 2; c++)
            qa[rt][c] = *(const f16_8*)&qh[(size_t)(qw + rt*16 + l15)*64 + c*32 + quad*8];

    f32_4 o[2][4] = {};
    float m_r[2][4], l_r[2][4];
    #pragma unroll
    for (int rt = 0; rt < 2; rt++)
        #pragma unroll
        for (int r = 0; r < 4; r++) { m_r[rt][r] = NEG_INF; l_r[rt][r] = 0.f; }

    const int ntiles = 2*qb + 2;
    const int sk = t >> 2;          // 0..63 (key row for Ks, hd row for Vs)
    const int sc = (t & 3) * 8;     // 0,8,16,24

    for (int kt = 0; kt < ntiles; kt++) {
        const int kbase = kt * 64;
        // stage K [key][hd] and V^T [hd][key]: pure coalesced 16B copies
        *(uint4*)&Ks[sk*72 + sc]      = *(const uint4*)&kh[(size_t)(kbase + sk)*64 + sc];
        *(uint4*)&Ks[sk*72 + sc + 32] = *(const uint4*)&kh[(size_t)(kbase + sk)*64 + sc + 32];
        *(uint4*)&Vs[sk*72 + sc]      = *(const uint4*)&vt[(size_t)sk*2048 + kbase + sc];
        *(uint4*)&Vs[sk*72 + sc + 32] = *(const uint4*)&vt[(size_t)sk*2048 + kbase + sc + 32];
        __syncthreads();

        if (kbase <= qw + 31) {     // wave-uniform: any of my rows see this tile
            // ---- S = Q K^T ----
            f16_8 kb[4][2];
            #pragma unroll
            for (int sub = 0; sub < 4; sub++)
                #pragma unroll
                for (int c = 0; c < 2; c++)
                    kb[sub][c] = *(const f16_8*)&Ks[(sub*16 + l15)*72 + c*32 + quad*8];
            f32_4 s[2][4];
            #pragma unroll
            for (int rt = 0; rt < 2; rt++)
                #pragma unroll
                for (int sub = 0; sub < 4; sub++) {
                    f32_4 acc = {};
                    acc = MFMA16(qa[rt][0], kb[sub][0], acc);
                    acc = MFMA16(qa[rt][1], kb[sub][1], acc);
                    s[rt][sub] = acc;
                }

            // ---- online softmax (exp2 domain) ----
            const bool masked = (kbase + 63 > qw);   // wave-uniform
            #pragma unroll
            for (int rt = 0; rt < 2; rt++)
            #pragma unroll
            for (int r = 0; r < 4; r++) {
                float v0 = s[rt][0][r], v1 = s[rt][1][r];
                float v2 = s[rt][2][r], v3 = s[rt][3][r];
                if (masked) {
                    const int row = qw + rt*16 + quad*4 + r;
                    v0 = (kbase      + l15 <= row) ? v0 : NEG_INF;
                    v1 = (kbase + 16 + l15 <= row) ? v1 : NEG_INF;
                    v2 = (kbase + 32 + l15 <= row) ? v2 : NEG_INF;
                    v3 = (kbase + 48 + l15 <= row) ? v3 : NEG_INF;
                }
                float mx = fmaxf(fmaxf(v0, v1), fmaxf(v2, v3));
                #pragma unroll
                for (int off = 1; off < 16; off <<= 1)
                    mx = fmaxf(mx, __shfl_xor(mx, off, 64));
                float nm = fmaxf(m_r[rt][r], mx);
                float p0 = __builtin_amdgcn_exp2f(v0 - nm);
                float p1 = __builtin_amdgcn_exp2f(v1 - nm);
                float p2 = __builtin_amdgcn_exp2f(v2 - nm);
                float p3 = __builtin_amdgcn_exp2f(v3 - nm);
                float sm = (p0 + p1) + (p2 + p3);
                #pragma unroll
                for (int off = 1; off < 16; off <<= 1)
                    sm += __shfl_xor(sm, off, 64);
                float al = __builtin_amdgcn_exp2f(m_r[rt][r] - nm);
                m_r[rt][r] = nm;
                l_r[rt][r] = l_r[rt][r]*al + sm;
                #pragma unroll
                for (int tt = 0; tt < 4; tt++) o[rt][tt][r] *= al;
                const int prow = (rt*16 + quad*4 + r)*72;
                Pl[w][prow +      l15] = (f16)p0;
                Pl[w][prow + 16 + l15] = (f16)p1;
                Pl[w][prow + 32 + l15] = (f16)p2;
                Pl[w][prow + 48 + l15] = (f16)p3;
            }
            asm volatile("s_waitcnt lgkmcnt(0)" ::: "memory");

            // ---- O += P V ----
            f16_8 vb[4][2];
            #pragma unroll
            for (int tt = 0; tt < 4; tt++)
                #pragma unroll
                for (int c = 0; c < 2; c++)
                    vb[tt][c] = *(const f16_8*)&Vs[(tt*16 + l15)*72 + c*32 + quad*8];
            #pragma unroll
            for (int rt = 0; rt < 2; rt++) {
                f16_8 pa0 = *(const f16_8*)&Pl[w][(rt*16 + l15)*72 +      quad*8];
                f16_8 pa1 = *(const f16_8*)&Pl[w][(rt*16 + l15)*72 + 32 + quad*8];
                #pragma unroll
                for (int tt = 0; tt < 4; tt++) {
                    o[rt][tt] = MFMA16(pa0, vb[tt][0], o[rt][tt]);
                    o[rt][tt] = MFMA16(pa1, vb[tt][1], o[rt][tt]);
                }
            }
        }
        __syncthreads();
    }

    // epilogue: normalize, write Y f16
    #pragma unroll
    for (int rt = 0; rt < 2; rt++)
    #pragma unroll
    for (int r = 0; r < 4; r++) {
        float inv = 1.0f / l_r[rt][r];
        int srow = qw + rt*16 + quad*4 + r;
        #pragma unroll
        for (int tt = 0; tt < 4; tt++) {
            int col = h*64 + tt*16 + l15;
            Y[(size_t)(b*S_ + srow)*1024 + col] = (f16)(o[rt][tt][r] * inv);
        }
    }
}

// ---------------------------------------------------------------------------
// GEMM2: out = y @ W_proj + b_proj  (A f16 from ws, B fp32->f16, C fp32)
// ---------------------------------------------------------------------------
__global__ __launch_bounds__(256) void proj_gemm(
    const f16* __restrict__ Yb,     // [8192,1024] f16
    const float* __restrict__ W,    // [1024,1024]
    const float* __restrict__ bias, // [1024]
    float* __restrict__ Out)        // [8192,1024]
{
    __shared__ f16 As[64*40];
    __shared__ f16 Bs[64*40];
    const int t    = threadIdx.x;
    const int lane = t & 63;
    const int w    = t >> 6;
    const int quad = lane >> 4, l15 = lane & 15;
    const int n0   = blockIdx.x * 64;
    const int m0   = blockIdx.y * 64;

    f32_4 c[2][2] = {};
    const int am = t >> 2, ak = (t & 3) * 8;
    const int bn = t & 63, bk = (t >> 6) * 8;
    const int mb = (w >> 1) * 32, nb = (w & 1) * 32;

    for (int k0 = 0; k0 < 1024; k0 += 32) {
        *(uint4*)&As[am*40 + ak] =
            *(const uint4*)&Yb[(size_t)(m0 + am)*1024 + k0 + ak];
        {
            f16 h[8];
            #pragma unroll
            for (int i = 0; i < 8; i++)
                h[i] = (f16)W[(size_t)(k0 + bk + i)*1024 + n0 + bn];
            *(uint4*)&Bs[bn*40 + bk] = *(const uint4*)h;
        }
        __syncthreads();
        f16_8 a0 = *(const f16_8*)&As[(mb      + l15)*40 + quad*8];
        f16_8 a1 = *(const f16_8*)&As[(mb + 16 + l15)*40 + quad*8];
        f16_8 b0 = *(const f16_8*)&Bs[(nb      + l15)*40 + quad*8];
        f16_8 b1 = *(const f16_8*)&Bs[(nb + 16 + l15)*40 + quad*8];
        c[0][0] = MFMA16(a0, b0, c[0][0]);
        c[0][1] = MFMA16(a0, b1, c[0][1]);
        c[1][0] = MFMA16(a1, b0, c[1][0]);
        c[1][1] = MFMA16(a1, b1, c[1][1]);
        __syncthreads();
    }
    #pragma unroll
    for (int mi = 0; mi < 2; mi++)
    #pragma unroll
    for (int ni = 0; ni < 2; ni++)
    #pragma unroll
    for (int r = 0; r < 4; r++) {
        int m = m0 + mb + mi*16 + quad*4 + r;
        int n = n0 + nb + ni*16 + l15;
        Out[(size_t)m*1024 + n] = c[mi][ni][r] + bias[n];
    }
}

// ---------------------------------------------------------------------------
extern "C" void kernel_launch(void* const* d_in, const int* in_sizes, int n_in,
                              void* d_out, int out_size, void* d_ws, size_t ws_size,
                              hipStream_t stream) {
    const float* x      = (const float*)d_in[0];
    const float* W_attn = (const float*)d_in[1];
    const float* b_attn = (const float*)d_in[2];
    const float* W_proj = (const float*)d_in[3];
    const float* b_proj = (const float*)d_in[4];
    float* out = (float*)d_out;

    const size_t per = (size_t)B_ * H_ * S_ * HD_;   // 8,388,608 elems
    f16* Qb = (f16*)d_ws;
    f16* Kb = Qb + per;
    f16* Vt = Kb + per;
    f16* Yb = Vt + per;                               // total 64 MB

    qkv_gemm<<<dim3(3*D_/64, BS_/64), 256, 0, stream>>>(x, W_attn, b_attn, Qb, Kb, Vt);
    attn    <<<dim3(S_/128, B_*H_),   256, 0, stream>>>(Qb, Kb, Vt, Yb);
    proj_gemm<<<dim3(D_/64, BS_/64),  256, 0, stream>>>(Yb, W_proj, b_proj, out);
}

// Round 4
// 301.128 us; speedup vs baseline: 1.9660x; 1.8018x over previous
//
#include <hip/hip_runtime.h>

#define B_  4
#define S_  2048
#define D_  1024
#define H_  16
#define HD_ 64
#define BS_ (B_*S_)   // 8192

typedef _Float16 f16;
typedef _Float16 f16_8 __attribute__((ext_vector_type(8)));
typedef float    f32_4 __attribute__((ext_vector_type(4)));
typedef unsigned int u32;

#define MFMA16(a,b,c) __builtin_amdgcn_mfma_f32_16x16x32_f16(a, b, c, 0, 0, 0)
#define NEG_INF (-__builtin_inff())

// async global->LDS, 16B per lane. lds chunk base must be wave-uniform.
__device__ inline void gl_lds16(const f16* g, f16* lds_base, int chunk_base) {
    __builtin_amdgcn_global_load_lds(
        (const __attribute__((address_space(1))) u32*)g,
        (__attribute__((address_space(3))) u32*)(lds_base + (size_t)chunk_base * 8),
        16, 0, 0);
}

// ---------------------------------------------------------------------------
// Transpose + convert: W [1024][ncols] fp32  ->  Wt [ncols][1024] f16
// (fixed: load phase now covers all 64 k-rows of the tile, 4 sub-loads)
// ---------------------------------------------------------------------------
__global__ __launch_bounds__(256) void trans_w(
    const float* __restrict__ W, f16* __restrict__ Wt, int ncols)
{
    __shared__ f16 T[64][72];
    const int t = threadIdx.x;
    const int n0 = blockIdx.x * 64, k0 = blockIdx.y * 64;
    const int nl4 = (t & 15) * 4;
    #pragma unroll
    for (int r = 0; r < 4; r++) {
        const int kl = (t >> 4) + r * 16;
        float4 v = *(const float4*)&W[(size_t)(k0 + kl) * ncols + n0 + nl4];
        T[nl4 + 0][kl] = (f16)v.x;
        T[nl4 + 1][kl] = (f16)v.y;
        T[nl4 + 2][kl] = (f16)v.z;
        T[nl4 + 3][kl] = (f16)v.w;
    }
    __syncthreads();
    const int nr = t >> 2, kc = (t & 3) * 16;
    *(uint4*)&Wt[(size_t)(n0 + nr) * 1024 + k0 + kc]     = *(uint4*)&T[nr][kc];
    *(uint4*)&Wt[(size_t)(n0 + nr) * 1024 + k0 + kc + 8] = *(uint4*)&T[nr][kc + 8];
}

// ---------------------------------------------------------------------------
// GEMM1: qkv = x @ W_attn + b_attn.  A fp32 (manual stage+cvt), B f16 [n][k]
// via global_load_lds.  128x128 tile, BK=32.
//   Q -> [bh][s][hd] f16 scaled by 0.125*log2(e);  K -> [bh][s][hd] f16
//   V -> [bh][hd][s] f16 (transposed via LDS epilogue, coalesced stores)
// ---------------------------------------------------------------------------
__global__ __launch_bounds__(256) void qkv_gemm(
    const float* __restrict__ X,     // [8192,1024]
    const f16*   __restrict__ Wta,   // [3072,1024] f16 (pre-transposed)
    const float* __restrict__ bias,  // [3072]
    f16* __restrict__ Qb, f16* __restrict__ Kb, f16* __restrict__ Vt)
{
    __shared__ f16 lds[17408];          // 34.8 KB
    f16* Af = lds;                      // [128][40] padded
    f16* Bs = lds + 128*40;             // [128][32] unpadded (async dest)
    f16* Ct = lds;                      // [128][136] epilogue reuse

    const int t    = threadIdx.x;
    const int lane = t & 63;
    const int w    = t >> 6;
    const int quad = lane >> 4, l15 = lane & 15;
    const int wr = w >> 1, wc = w & 1;
    const int n0 = blockIdx.x * 128;
    const int m0 = blockIdx.y * 128;

    f32_4 acc[4][4] = {};
    const int am = t >> 1, ak = (t & 1) * 16;
    const int wbase = t & 192;          // wave-uniform

    for (int k0 = 0; k0 < 1024; k0 += 32) {
        // async stage B: [n][k] tile 128x32 f16, 2 calls
        #pragma unroll
        for (int c = 0; c < 2; c++) {
            int i = c*256 + t;
            gl_lds16(Wta + (size_t)(n0 + (i >> 2)) * 1024 + k0 + (i & 3) * 8,
                     Bs, c*256 + wbase);
        }
        // manual stage A: fp32 -> f16, 16 elems/thread
        {
            const float* xs = X + (size_t)(m0 + am) * 1024 + k0 + ak;
            float4 a0 = *(const float4*)(xs);
            float4 a1 = *(const float4*)(xs + 4);
            float4 a2 = *(const float4*)(xs + 8);
            float4 a3 = *(const float4*)(xs + 12);
            f16 hb[16] = {(f16)a0.x,(f16)a0.y,(f16)a0.z,(f16)a0.w,
                          (f16)a1.x,(f16)a1.y,(f16)a1.z,(f16)a1.w,
                          (f16)a2.x,(f16)a2.y,(f16)a2.z,(f16)a2.w,
                          (f16)a3.x,(f16)a3.y,(f16)a3.z,(f16)a3.w};
            *(uint4*)&Af[am*40 + ak]     = *(uint4*)&hb[0];
            *(uint4*)&Af[am*40 + ak + 8] = *(uint4*)&hb[8];
        }
        __syncthreads();   // drains vmcnt (async B) + lgkm

        f16_8 af[4], bf[4];
        #pragma unroll
        for (int mi = 0; mi < 4; mi++)
            af[mi] = *(const f16_8*)&Af[(wr*64 + mi*16 + l15)*40 + quad*8];
        #pragma unroll
        for (int ni = 0; ni < 4; ni++)
            bf[ni] = *(const f16_8*)&Bs[(wc*64 + ni*16 + l15)*32 + quad*8];
        #pragma unroll
        for (int mi = 0; mi < 4; mi++)
            #pragma unroll
            for (int ni = 0; ni < 4; ni++)
                acc[mi][ni] = MFMA16(af[mi], bf[ni], acc[mi][ni]);
        __syncthreads();
    }

    const int which = n0 >> 10;      // 0=Q 1=K 2=V (block-uniform)
    float bcol[4];
    #pragma unroll
    for (int ni = 0; ni < 4; ni++)
        bcol[ni] = bias[n0 + wc*64 + ni*16 + l15];

    if (which < 2) {
        f16* dst = (which == 0) ? Qb : Kb;
        const float sc = (which == 0) ? 0.125f * 1.44269504f : 1.0f;
        #pragma unroll
        for (int mi = 0; mi < 4; mi++)
        #pragma unroll
        for (int ni = 0; ni < 4; ni++)
        #pragma unroll
        for (int r = 0; r < 4; r++) {
            int m = m0 + wr*64 + mi*16 + quad*4 + r;
            int n = (n0 & 1023) + wc*64 + ni*16 + l15;
            int h = n >> 6, hd = n & 63;
            int b = m >> 11, s = m & 2047;
            dst[((size_t)(b*16 + h)*2048 + s)*64 + hd] =
                (f16)((acc[mi][ni][r] + bcol[ni]) * sc);
        }
    } else {
        // V: transpose via LDS, then coalesced stores along s
        #pragma unroll
        for (int mi = 0; mi < 4; mi++)
        #pragma unroll
        for (int ni = 0; ni < 4; ni++)
        #pragma unroll
        for (int r = 0; r < 4; r++) {
            int nl = wc*64 + ni*16 + l15;
            int ml = wr*64 + mi*16 + quad*4 + r;
            Ct[nl*136 + ml] = (f16)(acc[mi][ni][r] + bcol[ni]);
        }
        __syncthreads();
        const int row = t >> 1, sc4 = (t & 1) * 64;
        const int n = (n0 & 1023) + row;
        const int h = n >> 6, hd = n & 63;
        const int b = m0 >> 11, s0 = (m0 & 2047) + sc4;
        f16* dst = Vt + ((size_t)(b*16 + h)*64 + hd)*2048 + s0;
        #pragma unroll
        for (int j = 0; j < 8; j++)
            *(uint4*)&dst[j*8] = *(uint4*)&Ct[row*136 + sc4 + j*8];
    }
}

// ---------------------------------------------------------------------------
// Flash causal attention, balanced: block = (bh, strip-pair {qb, 15-qb}),
// 34 key-tiles per block uniformly. Fixed-max softmax (exp2 domain, max=0),
// row-sum l via MFMA against ones.
// ---------------------------------------------------------------------------
__global__ __launch_bounds__(256) void attn(
    const f16* __restrict__ Qb,
    const f16* __restrict__ Kb,
    const f16* __restrict__ Vt,     // [bh][hd][s]
    f16* __restrict__ Y)            // [8192,1024]
{
    __shared__ f16 Ks[64*72];       // [key][hd]
    __shared__ f16 Vs[64*72];       // [hd][key]
    __shared__ f16 Pl[4][32*72];

    const int t    = threadIdx.x;
    const int w    = t >> 6;
    const int lane = t & 63;
    const int quad = lane >> 4, l15 = lane & 15;
    const int bh   = blockIdx.y;
    const int b    = bh >> 4, h = bh & 15;

    const f16* qh = Qb + (size_t)bh * S_ * 64;
    const f16* kh = Kb + (size_t)bh * S_ * 64;
    const f16* vt = Vt + (size_t)bh * 64 * S_;

    const int sk = t >> 2, sc = (t & 3) * 8;
    const f16_8 ones = {(f16)1,(f16)1,(f16)1,(f16)1,(f16)1,(f16)1,(f16)1,(f16)1};

    #pragma unroll 1
    for (int sp = 0; sp < 2; sp++) {
        const int qb = sp ? 15 - (int)blockIdx.x : (int)blockIdx.x;
        const int qw = qb*128 + w*32;

        f16_8 qa[2][2];
        #pragma unroll
        for (int rt = 0; rt < 2; rt++)
            #pragma unroll
            for (int c = 0; c < 2; c++)
                qa[rt][c] = *(const f16_8*)&qh[(size_t)(qw + rt*16 + l15)*64 + c*32 + quad*8];

        f32_4 o[2][4] = {};
        f32_4 lacc[2] = {};
        const int ntiles = 2*qb + 2;

        for (int kt = 0; kt < ntiles; kt++) {
            const int kbase = kt * 64;
            *(uint4*)&Ks[sk*72 + sc]      = *(const uint4*)&kh[(size_t)(kbase + sk)*64 + sc];
            *(uint4*)&Ks[sk*72 + sc + 32] = *(const uint4*)&kh[(size_t)(kbase + sk)*64 + sc + 32];
            *(uint4*)&Vs[sk*72 + sc]      = *(const uint4*)&vt[(size_t)sk*2048 + kbase + sc];
            *(uint4*)&Vs[sk*72 + sc + 32] = *(const uint4*)&vt[(size_t)sk*2048 + kbase + sc + 32];
            __syncthreads();

            if (kbase <= qw + 31) {
                // ---- S = Q K^T ----
                f16_8 kb[4][2];
                #pragma unroll
                for (int sub = 0; sub < 4; sub++)
                    #pragma unroll
                    for (int c = 0; c < 2; c++)
                        kb[sub][c] = *(const f16_8*)&Ks[(sub*16 + l15)*72 + c*32 + quad*8];
                f32_4 s[2][4];
                #pragma unroll
                for (int rt = 0; rt < 2; rt++)
                    #pragma unroll
                    for (int sub = 0; sub < 4; sub++) {
                        f32_4 a = {};
                        a = MFMA16(qa[rt][0], kb[sub][0], a);
                        a = MFMA16(qa[rt][1], kb[sub][1], a);
                        s[rt][sub] = a;
                    }

                // ---- p = exp2(s) (fixed max), write P to LDS ----
                const bool masked = (kbase + 63 > qw);
                #pragma unroll
                for (int rt = 0; rt < 2; rt++)
                #pragma unroll
                for (int r = 0; r < 4; r++) {
                    float v0 = s[rt][0][r], v1 = s[rt][1][r];
                    float v2 = s[rt][2][r], v3 = s[rt][3][r];
                    if (masked) {
                        const int row = qw + rt*16 + quad*4 + r;
                        v0 = (kbase      + l15 <= row) ? v0 : NEG_INF;
                        v1 = (kbase + 16 + l15 <= row) ? v1 : NEG_INF;
                        v2 = (kbase + 32 + l15 <= row) ? v2 : NEG_INF;
                        v3 = (kbase + 48 + l15 <= row) ? v3 : NEG_INF;
                    }
                    const int prow = (rt*16 + quad*4 + r)*72;
                    Pl[w][prow +      l15] = (f16)__builtin_amdgcn_exp2f(v0);
                    Pl[w][prow + 16 + l15] = (f16)__builtin_amdgcn_exp2f(v1);
                    Pl[w][prow + 32 + l15] = (f16)__builtin_amdgcn_exp2f(v2);
                    Pl[w][prow + 48 + l15] = (f16)__builtin_amdgcn_exp2f(v3);
                }
                asm volatile("s_waitcnt lgkmcnt(0)" ::: "memory");

                // ---- O += P V ; l += P . 1 ----
                f16_8 vb[4][2];
                #pragma unroll
                for (int tt = 0; tt < 4; tt++)
                    #pragma unroll
                    for (int c = 0; c < 2; c++)
                        vb[tt][c] = *(const f16_8*)&Vs[(tt*16 + l15)*72 + c*32 + quad*8];
                #pragma unroll
                for (int rt = 0; rt < 2; rt++) {
                    f16_8 pa0 = *(const f16_8*)&Pl[w][(rt*16 + l15)*72 +      quad*8];
                    f16_8 pa1 = *(const f16_8*)&Pl[w][(rt*16 + l15)*72 + 32 + quad*8];
                    lacc[rt] = MFMA16(pa0, ones, lacc[rt]);
                    lacc[rt] = MFMA16(pa1, ones, lacc[rt]);
                    #pragma unroll
                    for (int tt = 0; tt < 4; tt++) {
                        o[rt][tt] = MFMA16(pa0, vb[tt][0], o[rt][tt]);
                        o[rt][tt] = MFMA16(pa1, vb[tt][1], o[rt][tt]);
                    }
                }
            }
            __syncthreads();
        }

        // epilogue: normalize, write Y
        #pragma unroll
        for (int rt = 0; rt < 2; rt++)
        #pragma unroll
        for (int r = 0; r < 4; r++) {
            float inv = 1.0f / lacc[rt][r];
            int srow = qw + rt*16 + quad*4 + r;
            #pragma unroll
            for (int tt = 0; tt < 4; tt++)
                Y[(size_t)(b*S_ + srow)*1024 + h*64 + tt*16 + l15] =
                    (f16)(o[rt][tt][r] * inv);
        }
    }
}

// ---------------------------------------------------------------------------
// GEMM2: out = y @ W_proj + b_proj.  Both operands f16 [.][k], full async.
// ---------------------------------------------------------------------------
__global__ __launch_bounds__(256) void proj_gemm(
    const f16* __restrict__ Yb,     // [8192,1024]
    const f16* __restrict__ Wtp,    // [1024,1024] (pre-transposed)
    const float* __restrict__ bias, // [1024]
    float* __restrict__ Out)        // [8192,1024] fp32
{
    __shared__ f16 lds2[128*32*2];
    f16* Af = lds2;                 // [128][32]
    f16* Bs = lds2 + 128*32;        // [128][32]

    const int t    = threadIdx.x;
    const int lane = t & 63;
    const int w    = t >> 6;
    const int quad = lane >> 4, l15 = lane & 15;
    const int wr = w >> 1, wc = w & 1;
    const int n0 = blockIdx.x * 128;
    const int m0 = blockIdx.y * 128;
    const int wbase = t & 192;

    f32_4 acc[4][4] = {};

    for (int k0 = 0; k0 < 1024; k0 += 32) {
        #pragma unroll
        for (int c = 0; c < 2; c++) {
            int i = c*256 + t;
            gl_lds16(Yb  + (size_t)(m0 + (i >> 2)) * 1024 + k0 + (i & 3) * 8, Af, c*256 + wbase);
            gl_lds16(Wtp + (size_t)(n0 + (i >> 2)) * 1024 + k0 + (i & 3) * 8, Bs, c*256 + wbase);
        }
        __syncthreads();
        f16_8 af[4], bf[4];
        #pragma unroll
        for (int mi = 0; mi < 4; mi++)
            af[mi] = *(const f16_8*)&Af[(wr*64 + mi*16 + l15)*32 + quad*8];
        #pragma unroll
        for (int ni = 0; ni < 4; ni++)
            bf[ni] = *(const f16_8*)&Bs[(wc*64 + ni*16 + l15)*32 + quad*8];
        #pragma unroll
        for (int mi = 0; mi < 4; mi++)
            #pragma unroll
            for (int ni = 0; ni < 4; ni++)
                acc[mi][ni] = MFMA16(af[mi], bf[ni], acc[mi][ni]);
        __syncthreads();
    }

    #pragma unroll
    for (int mi = 0; mi < 4; mi++)
    #pragma unroll
    for (int ni = 0; ni < 4; ni++)
    #pragma unroll
    for (int r = 0; r < 4; r++) {
        int m = m0 + wr*64 + mi*16 + quad*4 + r;
        int n = n0 + wc*64 + ni*16 + l15;
        Out[(size_t)m*1024 + n] = acc[mi][ni][r] + bias[n];
    }
}

// ---------------------------------------------------------------------------
extern "C" void kernel_launch(void* const* d_in, const int* in_sizes, int n_in,
                              void* d_out, int out_size, void* d_ws, size_t ws_size,
                              hipStream_t stream) {
    const float* x      = (const float*)d_in[0];
    const float* W_attn = (const float*)d_in[1];
    const float* b_attn = (const float*)d_in[2];
    const float* W_proj = (const float*)d_in[3];
    const float* b_proj = (const float*)d_in[4];
    float* out = (float*)d_out;

    const size_t per = (size_t)B_ * H_ * S_ * HD_;   // 8,388,608 elems
    f16* Yb  = (f16*)d_ws;        // [0, per)      attn output
    f16* Wta = Yb;                //   alias: W_attn^T f16 (dead before Yb written)
    f16* Qb  = Yb + per;          // [per, 2per)
    f16* Kb  = Qb + per;          // [2per, 3per)
    f16* Vt  = Kb + per;          // [3per, 4per)  total 67.1 MB
    f16* Wtp = Qb;                //   alias: W_proj^T f16 (written after attn)

    trans_w  <<<dim3(48, 16), 256, 0, stream>>>(W_attn, Wta, 3*D_);
    qkv_gemm <<<dim3(24, 64), 256, 0, stream>>>(x, Wta, b_attn, Qb, Kb, Vt);
    attn     <<<dim3(8, 64),  256, 0, stream>>>(Qb, Kb, Vt, Yb);
    trans_w  <<<dim3(16, 16), 256, 0, stream>>>(W_proj, Wtp, D_);
    proj_gemm<<<dim3(8, 64),  256, 0, stream>>>(Yb, Wtp, b_proj, out);
}

// Round 5
// 284.800 us; speedup vs baseline: 2.0787x; 1.0573x over previous
//
#include <hip/hip_runtime.h>

#define B_  4
#define S_  2048
#define D_  1024
#define H_  16
#define HD_ 64
#define BS_ (B_*S_)   // 8192

typedef _Float16 f16;
typedef _Float16 f16_8 __attribute__((ext_vector_type(8)));
typedef _Float16 f16_4 __attribute__((ext_vector_type(4)));
typedef float    f32_4 __attribute__((ext_vector_type(4)));
typedef unsigned int u32;

#define MFMA32(a,b,c) __builtin_amdgcn_mfma_f32_16x16x32_f16(a, b, c, 0, 0, 0)
#define MFMA16(a,b,c) __builtin_amdgcn_mfma_f32_16x16x16f16(a, b, c, 0, 0, 0)
#define NEG_INF (-__builtin_inff())

// async global->LDS, 16B per lane. chunk_base in lane units (16B each).
__device__ inline void gl_lds16(const f16* g, f16* lds_base, int chunk_base) {
    __builtin_amdgcn_global_load_lds(
        (const __attribute__((address_space(1))) u32*)g,
        (__attribute__((address_space(3))) u32*)(lds_base + (size_t)chunk_base * 8),
        16, 0, 0);
}

// ---------------------------------------------------------------------------
// X fp32 -> f16 (into d_out scratch; d_out is dead until proj_gemm)
// ---------------------------------------------------------------------------
__global__ __launch_bounds__(256) void x2h(
    const float* __restrict__ X, f16* __restrict__ Xh)
{
    const size_t i = ((size_t)blockIdx.x * 256 + threadIdx.x) * 8;
    float4 a = *(const float4*)&X[i];
    float4 b = *(const float4*)&X[i + 4];
    f16 h[8] = {(f16)a.x,(f16)a.y,(f16)a.z,(f16)a.w,
                (f16)b.x,(f16)b.y,(f16)b.z,(f16)b.w};
    *(uint4*)&Xh[i] = *(const uint4*)h;
}

// ---------------------------------------------------------------------------
// Transpose + convert: W [1024][ncols] fp32 -> Wt [ncols][1024] f16
// ---------------------------------------------------------------------------
__global__ __launch_bounds__(256) void trans_w(
    const float* __restrict__ W, f16* __restrict__ Wt, int ncols)
{
    __shared__ f16 T[64][72];
    const int t = threadIdx.x;
    const int n0 = blockIdx.x * 64, k0 = blockIdx.y * 64;
    const int nl4 = (t & 15) * 4;
    #pragma unroll
    for (int r = 0; r < 4; r++) {
        const int kl = (t >> 4) + r * 16;
        float4 v = *(const float4*)&W[(size_t)(k0 + kl) * ncols + n0 + nl4];
        T[nl4 + 0][kl] = (f16)v.x;
        T[nl4 + 1][kl] = (f16)v.y;
        T[nl4 + 2][kl] = (f16)v.z;
        T[nl4 + 3][kl] = (f16)v.w;
    }
    __syncthreads();
    const int nr = t >> 2, kc = (t & 3) * 16;
    *(uint4*)&Wt[(size_t)(n0 + nr) * 1024 + k0 + kc]     = *(uint4*)&T[nr][kc];
    *(uint4*)&Wt[(size_t)(n0 + nr) * 1024 + k0 + kc + 8] = *(uint4*)&T[nr][kc + 8];
}

// ---------------------------------------------------------------------------
// GEMM1: qkv = x @ W_attn + b_attn.  Both operands f16, full async staging,
// 128x128 tile, BK=64 as 2x[128][32] chunks (m97 read pattern).
// ---------------------------------------------------------------------------
__global__ __launch_bounds__(256) void qkv_gemm(
    const f16*   __restrict__ Xh,    // [8192,1024] f16
    const f16*   __restrict__ Wta,   // [3072,1024] f16 (pre-transposed)
    const float* __restrict__ bias,  // [3072]
    f16* __restrict__ Qb, f16* __restrict__ Kb, f16* __restrict__ Vt)
{
    __shared__ f16 lds[17408];          // 34.8 KB (epilogue Ct reuse)
    f16* Af[2] = {lds,        lds + 4096};
    f16* Bf[2] = {lds + 8192, lds + 12288};
    f16* Ct    = lds;                   // [128][136]

    const int t    = threadIdx.x;
    const int lane = t & 63;
    const int w    = t >> 6;
    const int quad = lane >> 4, l15 = lane & 15;
    const int wr = w >> 1, wc = w & 1;
    const int n0 = blockIdx.x * 128;
    const int m0 = blockIdx.y * 128;
    const int wbase = t & 192;          // wave-uniform

    f32_4 acc[4][4] = {};

    for (int k0 = 0; k0 < 1024; k0 += 64) {
        #pragma unroll
        for (int kc = 0; kc < 2; kc++)
            #pragma unroll
            for (int c = 0; c < 2; c++) {
                int i = c*256 + t;
                const int row = i >> 2, col = (i & 3) * 8;
                gl_lds16(Xh  + (size_t)(m0 + row)*1024 + k0 + kc*32 + col,
                         Af[kc], c*256 + wbase);
                gl_lds16(Wta + (size_t)(n0 + row)*1024 + k0 + kc*32 + col,
                         Bf[kc], c*256 + wbase);
            }
        __syncthreads();   // drains vmcnt + lgkm

        #pragma unroll
        for (int kc = 0; kc < 2; kc++) {
            f16_8 af[4], bf[4];
            #pragma unroll
            for (int mi = 0; mi < 4; mi++)
                af[mi] = *(const f16_8*)&Af[kc][(wr*64 + mi*16 + l15)*32 + quad*8];
            #pragma unroll
            for (int ni = 0; ni < 4; ni++)
                bf[ni] = *(const f16_8*)&Bf[kc][(wc*64 + ni*16 + l15)*32 + quad*8];
            #pragma unroll
            for (int mi = 0; mi < 4; mi++)
                #pragma unroll
                for (int ni = 0; ni < 4; ni++)
                    acc[mi][ni] = MFMA32(af[mi], bf[ni], acc[mi][ni]);
        }
        __syncthreads();
    }

    const int which = n0 >> 10;      // 0=Q 1=K 2=V (block-uniform)
    float bcol[4];
    #pragma unroll
    for (int ni = 0; ni < 4; ni++)
        bcol[ni] = bias[n0 + wc*64 + ni*16 + l15];

    if (which < 2) {
        f16* dst = (which == 0) ? Qb : Kb;
        const float sc = (which == 0) ? 0.125f * 1.44269504f : 1.0f;
        #pragma unroll
        for (int mi = 0; mi < 4; mi++)
        #pragma unroll
        for (int ni = 0; ni < 4; ni++)
        #pragma unroll
        for (int r = 0; r < 4; r++) {
            int m = m0 + wr*64 + mi*16 + quad*4 + r;
            int n = (n0 & 1023) + wc*64 + ni*16 + l15;
            int h = n >> 6, hd = n & 63;
            int b = m >> 11, s = m & 2047;
            dst[((size_t)(b*16 + h)*2048 + s)*64 + hd] =
                (f16)((acc[mi][ni][r] + bcol[ni]) * sc);
        }
    } else {
        // V: transpose via LDS, coalesced stores along s
        #pragma unroll
        for (int mi = 0; mi < 4; mi++)
        #pragma unroll
        for (int ni = 0; ni < 4; ni++)
        #pragma unroll
        for (int r = 0; r < 4; r++) {
            int nl = wc*64 + ni*16 + l15;
            int ml = wr*64 + mi*16 + quad*4 + r;
            Ct[nl*136 + ml] = (f16)(acc[mi][ni][r] + bcol[ni]);
        }
        __syncthreads();
        const int row = t >> 1, sc4 = (t & 1) * 64;
        const int n = (n0 & 1023) + row;
        const int h = n >> 6, hd = n & 63;
        const int b = m0 >> 11, s0 = (m0 & 2047) + sc4;
        f16* dst = Vt + ((size_t)(b*16 + h)*64 + hd)*2048 + s0;
        #pragma unroll
        for (int j = 0; j < 8; j++)
            *(uint4*)&dst[j*8] = *(uint4*)&Ct[row*136 + sc4 + j*8];
    }
}

// ---------------------------------------------------------------------------
// Flash causal attention, balanced strip-pairs, fixed-max exp2 softmax.
// S^T = K*Q^T so P^T's C-layout IS the 16x16x16 A-operand layout:
// no LDS round-trip for P.  l via MFMA against ones.
// ---------------------------------------------------------------------------
__global__ __launch_bounds__(256) void attn(
    const f16* __restrict__ Qb,
    const f16* __restrict__ Kb,
    const f16* __restrict__ Vt,     // [bh][hd][s]
    f16* __restrict__ Y)            // [8192,1024]
{
    __shared__ f16 Ks[64*72];       // [key][hd]
    __shared__ f16 Vs[64*72];       // [hd][key]

    const int t    = threadIdx.x;
    const int w    = t >> 6;
    const int lane = t & 63;
    const int quad = lane >> 4, l15 = lane & 15;
    const int bh   = blockIdx.y;
    const int b    = bh >> 4, h = bh & 15;

    const f16* qh = Qb + (size_t)bh * S_ * 64;
    const f16* kh = Kb + (size_t)bh * S_ * 64;
    const f16* vt = Vt + (size_t)bh * 64 * S_;

    const int sk = t >> 2, sc = (t & 3) * 8;
    const f16_4 ones = {(f16)1,(f16)1,(f16)1,(f16)1};

    #pragma unroll 1
    for (int sp = 0; sp < 2; sp++) {
        const int qb = sp ? 15 - (int)blockIdx.x : (int)blockIdx.x;
        const int qw = qb*128 + w*32;

        f16_8 qa[2][2];
        #pragma unroll
        for (int rt = 0; rt < 2; rt++)
            #pragma unroll
            for (int c = 0; c < 2; c++)
                qa[rt][c] = *(const f16_8*)&qh[(size_t)(qw + rt*16 + l15)*64 + c*32 + quad*8];

        f32_4 o[2][4] = {};
        f32_4 lacc[2] = {};
        const int ntiles = 2*qb + 2;

        for (int kt = 0; kt < ntiles; kt++) {
            const int kbase = kt * 64;
            *(uint4*)&Ks[sk*72 + sc]      = *(const uint4*)&kh[(size_t)(kbase + sk)*64 + sc];
            *(uint4*)&Ks[sk*72 + sc + 32] = *(const uint4*)&kh[(size_t)(kbase + sk)*64 + sc + 32];
            *(uint4*)&Vs[sk*72 + sc]      = *(const uint4*)&vt[(size_t)sk*2048 + kbase + sc];
            *(uint4*)&Vs[sk*72 + sc + 32] = *(const uint4*)&vt[(size_t)sk*2048 + kbase + sc + 32];
            __syncthreads();

            if (kbase <= qw + 31) {
                // ---- S^T = K Q^T : rows=key(quad*4+r), cols=qrow(l15) ----
                f16_8 kb[4][2];
                #pragma unroll
                for (int sub = 0; sub < 4; sub++)
                    #pragma unroll
                    for (int c = 0; c < 2; c++)
                        kb[sub][c] = *(const f16_8*)&Ks[(sub*16 + l15)*72 + c*32 + quad*8];
                f32_4 st[2][4];
                #pragma unroll
                for (int rt = 0; rt < 2; rt++)
                    #pragma unroll
                    for (int sub = 0; sub < 4; sub++) {
                        f32_4 a = {};
                        a = MFMA32(kb[sub][0], qa[rt][0], a);
                        a = MFMA32(kb[sub][1], qa[rt][1], a);
                        st[rt][sub] = a;
                    }

                // ---- P^T = exp2(S^T), packed as 16x16x16 A-fragments ----
                const bool masked = (kbase + 63 > qw);
                f16_4 pt[2][4];
                #pragma unroll
                for (int rt = 0; rt < 2; rt++)
                #pragma unroll
                for (int sub = 0; sub < 4; sub++) {
                    const int qrow = qw + rt*16 + l15;
                    f16_4 p;
                    #pragma unroll
                    for (int r = 0; r < 4; r++) {
                        float v = st[rt][sub][r];
                        if (masked) {
                            int key = kbase + sub*16 + quad*4 + r;
                            v = (key <= qrow) ? v : NEG_INF;
                        }
                        p[r] = (f16)__builtin_amdgcn_exp2f(v);
                    }
                    pt[rt][sub] = p;
                }

                // ---- O += P V ; l += P . 1  (16x16x16, P from registers) ----
                #pragma unroll
                for (int sub = 0; sub < 4; sub++) {
                    f16_4 vb[4];
                    #pragma unroll
                    for (int tt = 0; tt < 4; tt++)
                        vb[tt] = *(const f16_4*)&Vs[(tt*16 + l15)*72 + sub*16 + quad*4];
                    #pragma unroll
                    for (int rt = 0; rt < 2; rt++) {
                        lacc[rt] = MFMA16(pt[rt][sub], ones, lacc[rt]);
                        #pragma unroll
                        for (int tt = 0; tt < 4; tt++)
                            o[rt][tt] = MFMA16(pt[rt][sub], vb[tt], o[rt][tt]);
                    }
                }
            }
            __syncthreads();
        }

        // epilogue: normalize, write Y
        #pragma unroll
        for (int rt = 0; rt < 2; rt++)
        #pragma unroll
        for (int r = 0; r < 4; r++) {
            float inv = 1.0f / lacc[rt][r];
            int srow = qw + rt*16 + quad*4 + r;
            #pragma unroll
            for (int tt = 0; tt < 4; tt++)
                Y[(size_t)(b*S_ + srow)*1024 + h*64 + tt*16 + l15] =
                    (f16)(o[rt][tt][r] * inv);
        }
    }
}

// ---------------------------------------------------------------------------
// GEMM2: out = y @ W_proj + b_proj.  Full async, BK=64 double-chunk.
// ---------------------------------------------------------------------------
__global__ __launch_bounds__(256) void proj_gemm(
    const f16* __restrict__ Yb,     // [8192,1024]
    const f16* __restrict__ Wtp,    // [1024,1024] (pre-transposed)
    const float* __restrict__ bias, // [1024]
    float* __restrict__ Out)        // [8192,1024] fp32
{
    __shared__ f16 lds2[16384];     // 32 KB
    f16* Af[2] = {lds2,        lds2 + 4096};
    f16* Bf[2] = {lds2 + 8192, lds2 + 12288};

    const int t    = threadIdx.x;
    const int lane = t & 63;
    const int w    = t >> 6;
    const int quad = lane >> 4, l15 = lane & 15;
    const int wr = w >> 1, wc = w & 1;
    const int n0 = blockIdx.x * 128;
    const int m0 = blockIdx.y * 128;
    const int wbase = t & 192;

    f32_4 acc[4][4] = {};

    for (int k0 = 0; k0 < 1024; k0 += 64) {
        #pragma unroll
        for (int kc = 0; kc < 2; kc++)
            #pragma unroll
            for (int c = 0; c < 2; c++) {
                int i = c*256 + t;
                const int row = i >> 2, col = (i & 3) * 8;
                gl_lds16(Yb  + (size_t)(m0 + row)*1024 + k0 + kc*32 + col,
                         Af[kc], c*256 + wbase);
                gl_lds16(Wtp + (size_t)(n0 + row)*1024 + k0 + kc*32 + col,
                         Bf[kc], c*256 + wbase);
            }
        __syncthreads();
        #pragma unroll
        for (int kc = 0; kc < 2; kc++) {
            f16_8 af[4], bf[4];
            #pragma unroll
            for (int mi = 0; mi < 4; mi++)
                af[mi] = *(const f16_8*)&Af[kc][(wr*64 + mi*16 + l15)*32 + quad*8];
            #pragma unroll
            for (int ni = 0; ni < 4; ni++)
                bf[ni] = *(const f16_8*)&Bf[kc][(wc*64 + ni*16 + l15)*32 + quad*8];
            #pragma unroll
            for (int mi = 0; mi < 4; mi++)
                #pragma unroll
                for (int ni = 0; ni < 4; ni++)
                    acc[mi][ni] = MFMA32(af[mi], bf[ni], acc[mi][ni]);
        }
        __syncthreads();
    }

    #pragma unroll
    for (int mi = 0; mi < 4; mi++)
    #pragma unroll
    for (int ni = 0; ni < 4; ni++)
    #pragma unroll
    for (int r = 0; r < 4; r++) {
        int m = m0 + wr*64 + mi*16 + quad*4 + r;
        int n = n0 + wc*64 + ni*16 + l15;
        Out[(size_t)m*1024 + n] = acc[mi][ni][r] + bias[n];
    }
}

// ---------------------------------------------------------------------------
extern "C" void kernel_launch(void* const* d_in, const int* in_sizes, int n_in,
                              void* d_out, int out_size, void* d_ws, size_t ws_size,
                              hipStream_t stream) {
    const float* x      = (const float*)d_in[0];
    const float* W_attn = (const float*)d_in[1];
    const float* b_attn = (const float*)d_in[2];
    const float* W_proj = (const float*)d_in[3];
    const float* b_proj = (const float*)d_in[4];
    float* out = (float*)d_out;

    const size_t per = (size_t)B_ * H_ * S_ * HD_;   // 8,388,608 elems
    f16* Yb  = (f16*)d_ws;        // [0, per)      attn output
    f16* Wta = Yb;                //   alias: W_attn^T f16 (dead before Yb written)
    f16* Qb  = Yb + per;          // [per, 2per)
    f16* Kb  = Qb + per;          // [2per, 3per)
    f16* Vt  = Kb + per;          // [3per, 4per)  total 67.1 MB
    f16* Wtp = Qb;                //   alias: W_proj^T f16 (written after attn)
    f16* Xh  = (f16*)d_out;       //   scratch: d_out dead until proj_gemm

    x2h      <<<BS_*D_/(256*8), 256, 0, stream>>>(x, Xh);
    trans_w  <<<dim3(48, 16), 256, 0, stream>>>(W_attn, Wta, 3*D_);
    qkv_gemm <<<dim3(24, 64), 256, 0, stream>>>(Xh, Wta, b_attn, Qb, Kb, Vt);
    attn     <<<dim3(8, 64),  256, 0, stream>>>(Qb, Kb, Vt, Yb);
    trans_w  <<<dim3(16, 16), 256, 0, stream>>>(W_proj, Wtp, D_);
    proj_gemm<<<dim3(8, 64),  256, 0, stream>>>(Yb, Wtp, b_proj, out);
}